// Round 1
// baseline (166.765 us; speedup 1.0000x reference)
//
#include <hip/hip_runtime.h>
#include <hip/hip_bf16.h>

// Skeleton min/max normalization.
// Input:  skeleton (B, 17, 2) f32.  Output: same shape f32.
// Per row b: valid[j] = (x!=0 || y!=0); min/max per channel over valid joints;
// if no valid joint -> min=max=0 (which makes the formula the identity,
// matching the reference's where(has_valid, ...) fallback exactly).
// rng = max-min, rng==0 -> 1; out = (in - min) / rng.

#define NJ 17

__global__ __launch_bounds__(256) void skel_norm_kernel(
    const float2* __restrict__ in, float2* __restrict__ out, int B) {
  int b = blockIdx.x * blockDim.x + threadIdx.x;
  if (b >= B) return;

  const float2* p = in + (size_t)b * NJ;
  float2 v[NJ];
#pragma unroll
  for (int j = 0; j < NJ; ++j) v[j] = p[j];

  const float BIG = 3.402823466e38f;  // FLT_MAX, matches jnp.finfo(f32).max
  float mnx = BIG, mny = BIG, mxx = -BIG, mxy = -BIG;
  bool any_valid = false;
#pragma unroll
  for (int j = 0; j < NJ; ++j) {
    float x = v[j].x, y = v[j].y;
    bool valid = (x != 0.0f) || (y != 0.0f);
    any_valid = any_valid || valid;
    // select semantics (no divergence cost; becomes v_cndmask):
    mnx = valid ? fminf(mnx, x) : mnx;
    mny = valid ? fminf(mny, y) : mny;
    mxx = valid ? fmaxf(mxx, x) : mxx;
    mxy = valid ? fmaxf(mxy, y) : mxy;
  }
  if (!any_valid) { mnx = 0.0f; mny = 0.0f; mxx = 0.0f; mxy = 0.0f; }

  float rx = mxx - mnx; rx = (rx == 0.0f) ? 1.0f : rx;
  float ry = mxy - mny; ry = (ry == 0.0f) ? 1.0f : ry;

  float2* q = out + (size_t)b * NJ;
#pragma unroll
  for (int j = 0; j < NJ; ++j) {
    float2 r;
    r.x = (v[j].x - mnx) / rx;  // IEEE div to match numpy reference closely
    r.y = (v[j].y - mny) / ry;
    q[j] = r;
  }
}

extern "C" void kernel_launch(void* const* d_in, const int* in_sizes, int n_in,
                              void* d_out, int out_size, void* d_ws, size_t ws_size,
                              hipStream_t stream) {
  (void)n_in; (void)d_ws; (void)ws_size;
  const float2* in = (const float2*)d_in[0];
  float2* out = (float2*)d_out;
  int B = in_sizes[0] / (NJ * 2);  // flat element count -> rows
  int block = 256;
  int grid = (B + block - 1) / block;
  skel_norm_kernel<<<grid, block, 0, stream>>>(in, out, B);
}

// Round 2
// 122.325 us; speedup vs baseline: 1.3633x; 1.3633x over previous
//
#include <hip/hip_runtime.h>
#include <hip/hip_bf16.h>

// Skeleton min/max normalization, LDS-staged for coalescing.
// Input: skeleton (B, 17, 2) f32. Output: same shape f32.
// Row = 34 floats (136 B) -> per-thread global access is badly strided, so:
//   phase 1: block copies 256 rows (2176 float4) global->LDS, coalesced
//   phase 2: each thread normalizes its own row in LDS (stride-34, 4-way
//            bank conflict on b64 reads = ~1.58x on LDS phase only; fine)
//   phase 3: block copies LDS->global, coalesced
// no-valid-joint rows: min=max=0 makes the formula the identity, matching
// the reference's where(has_valid, ...) fallback exactly.

#define NJ 17
#define FPR 34                              // floats per row
#define ROWS_PER_BLOCK 256
#define TILE_FLOATS (ROWS_PER_BLOCK * FPR)  // 8704
#define TILE_F4 (TILE_FLOATS / 4)           // 2176

__global__ __launch_bounds__(256) void skel_norm_kernel(
    const float4* __restrict__ in4, float4* __restrict__ out4,
    const float* __restrict__ inf, float* __restrict__ outf, int B) {
  __shared__ float4 lds4[TILE_F4];
  float* lds = (float*)lds4;

  const int tid = threadIdx.x;
  const size_t base_row = (size_t)blockIdx.x * ROWS_PER_BLOCK;
  const int nrows =
      (int)(((size_t)B - base_row) < ROWS_PER_BLOCK ? ((size_t)B - base_row)
                                                    : ROWS_PER_BLOCK);
  const int nfloats = nrows * FPR;
  const int nf4 = nfloats >> 2;
  const size_t base_f = base_row * FPR;   // divisible by 4 (base_row % 256 == 0)
  const size_t base_f4 = base_f >> 2;

  // phase 1: coalesced load
  for (int i = tid; i < nf4; i += ROWS_PER_BLOCK)
    lds4[i] = in4[base_f4 + i];
  for (int i = (nf4 << 2) + tid; i < nfloats; i += ROWS_PER_BLOCK)  // odd-row tail
    lds[i] = inf[base_f + i];
  __syncthreads();

  // phase 2: per-thread row normalize (in-place in LDS)
  if (tid < nrows) {
    float* row = lds + tid * FPR;  // byte offset 136*tid, 8B aligned
    float2 v[NJ];
#pragma unroll
    for (int j = 0; j < NJ; ++j) v[j] = *(float2*)(row + 2 * j);

    const float BIG = 3.402823466e38f;  // FLT_MAX
    float mnx = BIG, mny = BIG, mxx = -BIG, mxy = -BIG;
    bool any_valid = false;
#pragma unroll
    for (int j = 0; j < NJ; ++j) {
      float x = v[j].x, y = v[j].y;
      bool valid = (x != 0.0f) || (y != 0.0f);
      any_valid = any_valid || valid;
      mnx = valid ? fminf(mnx, x) : mnx;
      mny = valid ? fminf(mny, y) : mny;
      mxx = valid ? fmaxf(mxx, x) : mxx;
      mxy = valid ? fmaxf(mxy, y) : mxy;
    }
    if (!any_valid) { mnx = 0.0f; mny = 0.0f; mxx = 0.0f; mxy = 0.0f; }

    float rx = mxx - mnx; rx = (rx == 0.0f) ? 1.0f : rx;
    float ry = mxy - mny; ry = (ry == 0.0f) ? 1.0f : ry;

#pragma unroll
    for (int j = 0; j < NJ; ++j) {
      float2 r;
      r.x = (v[j].x - mnx) / rx;  // IEEE div to match numpy closely
      r.y = (v[j].y - mny) / ry;
      *(float2*)(row + 2 * j) = r;
    }
  }
  __syncthreads();

  // phase 3: coalesced store
  for (int i = tid; i < nf4; i += ROWS_PER_BLOCK)
    out4[base_f4 + i] = lds4[i];
  for (int i = (nf4 << 2) + tid; i < nfloats; i += ROWS_PER_BLOCK)
    outf[base_f + i] = lds[i];
}

extern "C" void kernel_launch(void* const* d_in, const int* in_sizes, int n_in,
                              void* d_out, int out_size, void* d_ws, size_t ws_size,
                              hipStream_t stream) {
  (void)n_in; (void)d_ws; (void)ws_size; (void)out_size;
  const float* inf = (const float*)d_in[0];
  float* outf = (float*)d_out;
  int B = in_sizes[0] / (NJ * 2);
  int grid = (B + ROWS_PER_BLOCK - 1) / ROWS_PER_BLOCK;
  skel_norm_kernel<<<grid, ROWS_PER_BLOCK, 0, stream>>>(
      (const float4*)inf, (float4*)outf, inf, outf, B);
}

// Round 3
// 111.581 us; speedup vs baseline: 1.4946x; 1.0963x over previous
//
#include <hip/hip_runtime.h>
#include <hip/hip_bf16.h>

// Skeleton min/max normalization, LDS-staged for coalescing.
// (B, 17, 2) f32 -> same. Row = 34 floats (136 B).
//   phase 1: async global->LDS via global_load_lds width=16 (wave-linear
//            mapping: thread i copies float4 i -> LDS base + i*16, which is
//            exactly the HW's uniform-base + lane*size constraint)
//   phase 2: thread t normalizes row t in LDS (stride-34 -> 4-way bank
//            conflict on b64, ~1.58x on this phase only)
//   phase 3: coalesced LDS->global float4 stores
// Division replaced by v_rcp_f32 + mul: tolerance is 2e-2, rcp error ~1ulp.
// no-valid-joint rows: min=max=0 makes the formula the identity (matches ref).

#define NJ 17
#define FPR 34                       // floats per row
#define RPB 256                      // rows per block == threads per block
#define TILE_F4 ((RPB * FPR) / 4)    // 2176 float4 = 34,816 B LDS

typedef const __attribute__((address_space(1))) void* gas_p;
typedef __attribute__((address_space(3))) void* las_p;

__device__ __forceinline__ void load16_lds(const float4* g, float4* l) {
  __builtin_amdgcn_global_load_lds((gas_p)g, (las_p)l, 16, 0, 0);
}

template <bool FULL>
__global__ __launch_bounds__(256) void skel_norm_kernel(
    const float4* __restrict__ in4, float4* __restrict__ out4,
    const float* __restrict__ inf, float* __restrict__ outf, int B) {
  __shared__ float4 lds4[TILE_F4];
  float* lds = (float*)lds4;

  const int tid = threadIdx.x;
  const size_t base_row = (size_t)blockIdx.x * RPB;
  const size_t base_f = base_row * FPR;
  const size_t base_f4 = base_f >> 2;

  int nrows = RPB;
  if constexpr (FULL) {
    // phase 1: async direct-to-LDS, 8 full waves-worth + a half iteration
#pragma unroll
    for (int k = 0; k < 8; ++k)
      load16_lds(in4 + base_f4 + tid + k * 256, &lds4[tid + k * 256]);
    if (tid < TILE_F4 - 2048)  // 2176-2048=128: waves 0,1 fully active
      load16_lds(in4 + base_f4 + tid + 2048, &lds4[tid + 2048]);
  } else {
    nrows = (int)(((size_t)B - base_row) < RPB ? ((size_t)B - base_row) : RPB);
    const int nfloats = nrows * FPR;
    for (int i = tid; i < nfloats; i += RPB) lds[i] = inf[base_f + i];
  }
  __syncthreads();  // drains vmcnt(0) for the global_load_lds

  // phase 2: per-thread row normalize (in-place)
  if (tid < nrows) {
    float* row = lds + tid * FPR;  // 136*tid bytes, 8B aligned
    float2 v[NJ];
#pragma unroll
    for (int j = 0; j < NJ; ++j) v[j] = *(float2*)(row + 2 * j);

    const float BIG = 3.402823466e38f;  // FLT_MAX
    float mnx = BIG, mny = BIG, mxx = -BIG, mxy = -BIG;
    bool any_valid = false;
#pragma unroll
    for (int j = 0; j < NJ; ++j) {
      float x = v[j].x, y = v[j].y;
      bool valid = (x != 0.0f) || (y != 0.0f);
      any_valid = any_valid || valid;
      mnx = valid ? fminf(mnx, x) : mnx;
      mny = valid ? fminf(mny, y) : mny;
      mxx = valid ? fmaxf(mxx, x) : mxx;
      mxy = valid ? fmaxf(mxy, y) : mxy;
    }
    if (!any_valid) { mnx = 0.0f; mny = 0.0f; mxx = 0.0f; mxy = 0.0f; }

    float rx = mxx - mnx; rx = (rx == 0.0f) ? 1.0f : rx;
    float ry = mxy - mny; ry = (ry == 0.0f) ? 1.0f : ry;
    float rxi = __builtin_amdgcn_rcpf(rx);  // v_rcp_f32, ~1ulp — tol is 2e-2
    float ryi = __builtin_amdgcn_rcpf(ry);

#pragma unroll
    for (int j = 0; j < NJ; ++j) {
      float2 r;
      r.x = (v[j].x - mnx) * rxi;
      r.y = (v[j].y - mny) * ryi;
      *(float2*)(row + 2 * j) = r;
    }
  }
  __syncthreads();

  // phase 3: coalesced store
  if constexpr (FULL) {
#pragma unroll
    for (int k = 0; k < 8; ++k)
      out4[base_f4 + tid + k * 256] = lds4[tid + k * 256];
    if (tid < TILE_F4 - 2048)
      out4[base_f4 + tid + 2048] = lds4[tid + 2048];
  } else {
    const int nfloats = nrows * FPR;
    for (int i = tid; i < nfloats; i += RPB) outf[base_f + i] = lds[i];
  }
}

extern "C" void kernel_launch(void* const* d_in, const int* in_sizes, int n_in,
                              void* d_out, int out_size, void* d_ws, size_t ws_size,
                              hipStream_t stream) {
  (void)n_in; (void)d_ws; (void)ws_size; (void)out_size;
  const float* inf = (const float*)d_in[0];
  float* outf = (float*)d_out;
  int B = in_sizes[0] / (NJ * 2);
  int grid = (B + RPB - 1) / RPB;
  if (B % RPB == 0)
    skel_norm_kernel<true><<<grid, RPB, 0, stream>>>(
        (const float4*)inf, (float4*)outf, inf, outf, B);
  else
    skel_norm_kernel<false><<<grid, RPB, 0, stream>>>(
        (const float4*)inf, (float4*)outf, inf, outf, B);
}

// Round 4
// 109.538 us; speedup vs baseline: 1.5224x; 1.0187x over previous
//
#include <hip/hip_runtime.h>
#include <hip/hip_bf16.h>

// Skeleton min/max normalization, LDS-staged, single-wave blocks.
// (B, 17, 2) f32 -> same. Row = 34 floats (136 B).
// Block = 64 threads = 1 wave = 64 rows = 8704 B LDS -> 18 blocks/CU resident,
// so 18 independent load streams per CU keep HBM fed while individual waves
// sit at their vmcnt-draining barriers (R2's 4-wave blocks gang-stalled).
//   phase 1: global->LDS via global_load_lds width=16 (wave-linear mapping)
//   phase 2: thread t normalizes row t in LDS (stride-34 b64 = LDS BW floor,
//            16 B/bank/access -- not a fixable conflict)
//   phase 3: coalesced LDS->global float4 stores
// rcp+fma instead of div: tolerance is 2e-2, rcp error ~1ulp.
// no-valid-joint rows: min=max=0 makes the formula the identity (matches ref).

#define NJ 17
#define FPR 34                      // floats per row
#define RPB 64                      // rows per block == threads per block
#define TILE_F4 ((RPB * FPR) / 4)   // 544 float4 = 8704 B LDS
#define FULL_ROUNDS (TILE_F4 / RPB) // 8
#define TAIL (TILE_F4 - FULL_ROUNDS * RPB)  // 32

typedef const __attribute__((address_space(1))) void* gas_p;
typedef __attribute__((address_space(3))) void* las_p;

__device__ __forceinline__ void load16_lds(const float4* g, float4* l) {
  __builtin_amdgcn_global_load_lds((gas_p)g, (las_p)l, 16, 0, 0);
}

template <bool FULL>
__global__ __launch_bounds__(64) void skel_norm_kernel(
    const float4* __restrict__ in4, float4* __restrict__ out4,
    const float* __restrict__ inf, float* __restrict__ outf, int B) {
  __shared__ float4 lds4[TILE_F4];
  float* lds = (float*)lds4;

  const int tid = threadIdx.x;
  const size_t base_row = (size_t)blockIdx.x * RPB;
  const size_t base_f = base_row * FPR;
  const size_t base_f4 = base_f >> 2;

  int nrows = RPB;
  if constexpr (FULL) {
#pragma unroll
    for (int k = 0; k < FULL_ROUNDS; ++k)
      load16_lds(in4 + base_f4 + tid + k * RPB, &lds4[tid + k * RPB]);
    if (tid < TAIL)
      load16_lds(in4 + base_f4 + tid + FULL_ROUNDS * RPB,
                 &lds4[tid + FULL_ROUNDS * RPB]);
  } else {
    nrows = (int)(((size_t)B - base_row) < RPB ? ((size_t)B - base_row) : RPB);
    const int nfloats = nrows * FPR;
    for (int i = tid; i < nfloats; i += RPB) lds[i] = inf[base_f + i];
  }
  __syncthreads();  // drains vmcnt(0) for the global_load_lds; 1-wave block

  // phase 2: per-thread row normalize (in-place)
  if (tid < nrows) {
    float* row = lds + tid * FPR;  // 136*tid bytes, 8B aligned
    float2 v[NJ];
#pragma unroll
    for (int j = 0; j < NJ; ++j) v[j] = *(float2*)(row + 2 * j);

    const float BIG = 3.402823466e38f;  // FLT_MAX
    float mnx = BIG, mny = BIG, mxx = -BIG, mxy = -BIG;
    bool any_valid = false;
#pragma unroll
    for (int j = 0; j < NJ; ++j) {
      float x = v[j].x, y = v[j].y;
      bool valid = (x != 0.0f) || (y != 0.0f);
      any_valid = any_valid || valid;
      mnx = valid ? fminf(mnx, x) : mnx;
      mny = valid ? fminf(mny, y) : mny;
      mxx = valid ? fmaxf(mxx, x) : mxx;
      mxy = valid ? fmaxf(mxy, y) : mxy;
    }
    if (!any_valid) { mnx = 0.0f; mny = 0.0f; mxx = 0.0f; mxy = 0.0f; }

    float rx = mxx - mnx; rx = (rx == 0.0f) ? 1.0f : rx;
    float ry = mxy - mny; ry = (ry == 0.0f) ? 1.0f : ry;
    float rxi = __builtin_amdgcn_rcpf(rx);  // ~1ulp; tol is 2e-2
    float ryi = __builtin_amdgcn_rcpf(ry);
    float bx = -mnx * rxi;  // out = v*rcp + (-mn*rcp)  (1 fma/elem)
    float by = -mny * ryi;

#pragma unroll
    for (int j = 0; j < NJ; ++j) {
      float2 r;
      r.x = fmaf(v[j].x, rxi, bx);
      r.y = fmaf(v[j].y, ryi, by);
      *(float2*)(row + 2 * j) = r;
    }
  }
  __syncthreads();

  // phase 3: coalesced store
  if constexpr (FULL) {
#pragma unroll
    for (int k = 0; k < FULL_ROUNDS; ++k)
      out4[base_f4 + tid + k * RPB] = lds4[tid + k * RPB];
    if (tid < TAIL)
      out4[base_f4 + tid + FULL_ROUNDS * RPB] = lds4[tid + FULL_ROUNDS * RPB];
  } else {
    const int nfloats = nrows * FPR;
    for (int i = tid; i < nfloats; i += RPB) outf[base_f + i] = lds[i];
  }
}

extern "C" void kernel_launch(void* const* d_in, const int* in_sizes, int n_in,
                              void* d_out, int out_size, void* d_ws, size_t ws_size,
                              hipStream_t stream) {
  (void)n_in; (void)d_ws; (void)ws_size; (void)out_size;
  const float* inf = (const float*)d_in[0];
  float* outf = (float*)d_out;
  int B = in_sizes[0] / (NJ * 2);
  int grid = (B + RPB - 1) / RPB;
  if (B % RPB == 0)
    skel_norm_kernel<true><<<grid, RPB, 0, stream>>>(
        (const float4*)inf, (float4*)outf, inf, outf, B);
  else
    skel_norm_kernel<false><<<grid, RPB, 0, stream>>>(
        (const float4*)inf, (float4*)outf, inf, outf, B);
}

// Round 6
// 88.645 us; speedup vs baseline: 1.8813x; 1.2357x over previous
//
#include <hip/hip_runtime.h>
#include <hip/hip_bf16.h>

// Skeleton min/max normalization, LDS-staged, single-wave blocks.
// (B, 17, 2) f32 -> same. Row = 34 floats (136 B).
// Block = 64 threads = 1 wave = 64 rows = 8704 B LDS (18 blocks/CU).
//   phase 1: global->LDS via global_load_lds width=16 (wave-linear mapping),
//            loads left CACHED so input stays resident in the 256 MB L3
//   phase 2: thread t normalizes row t in LDS (stride-34 b64 = LDS BW floor)
//   phase 3: coalesced NON-TEMPORAL float4 stores -- writes are never re-read
//            by this kernel; nt keeps the 285 MB input from being evicted
//            from L3 by 313 MB of write-allocate traffic (R4 theory).
// rcp+fma instead of div: tolerance is 2e-2, rcp error ~1ulp.
// no-valid-joint rows: min=max=0 makes the formula the identity (matches ref).

#define NJ 17
#define FPR 34                      // floats per row
#define RPB 64                      // rows per block == threads per block
#define TILE_F4 ((RPB * FPR) / 4)   // 544 float4 = 8704 B LDS
#define FULL_ROUNDS (TILE_F4 / RPB) // 8
#define TAIL (TILE_F4 - FULL_ROUNDS * RPB)  // 32

typedef float f32x4 __attribute__((ext_vector_type(4)));  // nt-store-able

typedef const __attribute__((address_space(1))) void* gas_p;
typedef __attribute__((address_space(3))) void* las_p;

__device__ __forceinline__ void load16_lds(const f32x4* g, f32x4* l) {
  __builtin_amdgcn_global_load_lds((gas_p)g, (las_p)l, 16, 0, 0);
}

template <bool FULL>
__global__ __launch_bounds__(64) void skel_norm_kernel(
    const f32x4* __restrict__ in4, f32x4* __restrict__ out4,
    const float* __restrict__ inf, float* __restrict__ outf, int B) {
  __shared__ f32x4 lds4[TILE_F4];
  float* lds = (float*)lds4;

  const int tid = threadIdx.x;
  const size_t base_row = (size_t)blockIdx.x * RPB;
  const size_t base_f = base_row * FPR;
  const size_t base_f4 = base_f >> 2;

  int nrows = RPB;
  if constexpr (FULL) {
#pragma unroll
    for (int k = 0; k < FULL_ROUNDS; ++k)
      load16_lds(in4 + base_f4 + tid + k * RPB, &lds4[tid + k * RPB]);
    if (tid < TAIL)
      load16_lds(in4 + base_f4 + tid + FULL_ROUNDS * RPB,
                 &lds4[tid + FULL_ROUNDS * RPB]);
  } else {
    nrows = (int)(((size_t)B - base_row) < RPB ? ((size_t)B - base_row) : RPB);
    const int nfloats = nrows * FPR;
    for (int i = tid; i < nfloats; i += RPB) lds[i] = inf[base_f + i];
  }
  __syncthreads();  // drains vmcnt(0) for the global_load_lds; 1-wave block

  // phase 2: per-thread row normalize (in-place)
  if (tid < nrows) {
    float* row = lds + tid * FPR;  // 136*tid bytes, 8B aligned
    float2 v[NJ];
#pragma unroll
    for (int j = 0; j < NJ; ++j) v[j] = *(float2*)(row + 2 * j);

    const float BIG = 3.402823466e38f;  // FLT_MAX
    float mnx = BIG, mny = BIG, mxx = -BIG, mxy = -BIG;
    bool any_valid = false;
#pragma unroll
    for (int j = 0; j < NJ; ++j) {
      float x = v[j].x, y = v[j].y;
      bool valid = (x != 0.0f) || (y != 0.0f);
      any_valid = any_valid || valid;
      mnx = valid ? fminf(mnx, x) : mnx;
      mny = valid ? fminf(mny, y) : mny;
      mxx = valid ? fmaxf(mxx, x) : mxx;
      mxy = valid ? fmaxf(mxy, y) : mxy;
    }
    if (!any_valid) { mnx = 0.0f; mny = 0.0f; mxx = 0.0f; mxy = 0.0f; }

    float rx = mxx - mnx; rx = (rx == 0.0f) ? 1.0f : rx;
    float ry = mxy - mny; ry = (ry == 0.0f) ? 1.0f : ry;
    float rxi = __builtin_amdgcn_rcpf(rx);  // ~1ulp; tol is 2e-2
    float ryi = __builtin_amdgcn_rcpf(ry);
    float bx = -mnx * rxi;  // out = v*rcp + (-mn*rcp)  (1 fma/elem)
    float by = -mny * ryi;

#pragma unroll
    for (int j = 0; j < NJ; ++j) {
      float2 r;
      r.x = fmaf(v[j].x, rxi, bx);
      r.y = fmaf(v[j].y, ryi, by);
      *(float2*)(row + 2 * j) = r;
    }
  }
  __syncthreads();

  // phase 3: coalesced non-temporal store
  if constexpr (FULL) {
#pragma unroll
    for (int k = 0; k < FULL_ROUNDS; ++k)
      __builtin_nontemporal_store(lds4[tid + k * RPB],
                                  &out4[base_f4 + tid + k * RPB]);
    if (tid < TAIL)
      __builtin_nontemporal_store(lds4[tid + FULL_ROUNDS * RPB],
                                  &out4[base_f4 + tid + FULL_ROUNDS * RPB]);
  } else {
    const int nfloats = nrows * FPR;
    for (int i = tid; i < nfloats; i += RPB)
      __builtin_nontemporal_store(lds[i], &outf[base_f + i]);
  }
}

extern "C" void kernel_launch(void* const* d_in, const int* in_sizes, int n_in,
                              void* d_out, int out_size, void* d_ws, size_t ws_size,
                              hipStream_t stream) {
  (void)n_in; (void)d_ws; (void)ws_size; (void)out_size;
  const float* inf = (const float*)d_in[0];
  float* outf = (float*)d_out;
  int B = in_sizes[0] / (NJ * 2);
  int grid = (B + RPB - 1) / RPB;
  if (B % RPB == 0)
    skel_norm_kernel<true><<<grid, RPB, 0, stream>>>(
        (const f32x4*)inf, (f32x4*)outf, inf, outf, B);
  else
    skel_norm_kernel<false><<<grid, RPB, 0, stream>>>(
        (const f32x4*)inf, (f32x4*)outf, inf, outf, B);
}